// Round 2
// baseline (194.362 us; speedup 1.0000x reference)
//
#include <hip/hip_runtime.h>

// RoutingPooling: x [B=32, H=64, W=64, C=256] fp32 -> out [32, 32, 32, 256] fp32
// KERNEL=STRIDE=2 (non-overlapping 2x2 patches), ATOMS=4, g=C/4=64 groups,
// NUM_ROUTING=2, TEMPER=1.0. Closed form per (b,i,j,group):
//   pose0 = mean(v0..v3); l_k = <v_k, pose0>; r = softmax(l); out = sum r_k v_k
//
// Memory-bound: 128 MB in (each element read once) + 32 MB out = 160 MB.
// One thread per group: loads 4x float4 (coalesced across groups), stores 1x float4.

constexpr int Bn = 32, Hn = 64, Wn = 64;
constexpr int OH = 32, OW = 32, G = 64;  // C/ATOMS

__global__ __launch_bounds__(256) void routing_pool_kernel(
    const float4* __restrict__ x, float4* __restrict__ out) {
  long idx = (long)blockIdx.x * blockDim.x + threadIdx.x;
  // idx = ((b*OH + i)*OW + j)*G + gc ; gc fastest for coalescing
  int gc = (int)(idx & 63);
  long t = idx >> 6;
  int j = (int)(t & 31); t >>= 5;
  int i = (int)(t & 31); t >>= 5;
  int b = (int)t;

  // x viewed as float4: 64 float4 per (b,h,w) position
  long base = (((long)b * Hn + 2 * i) * Wn + 2 * j) * 64 + gc;
  const long rowstride = (long)Wn * 64;  // next h row, in float4 units

  float4 v0 = x[base];                  // (2i,   2j)   kk=0
  float4 v1 = x[base + 64];             // (2i,   2j+1) kk=1
  float4 v2 = x[base + rowstride];      // (2i+1, 2j)   kk=2
  float4 v3 = x[base + rowstride + 64]; // (2i+1, 2j+1) kk=3

  // pose0 = mean of votes
  float mx_ = (v0.x + v1.x + v2.x + v3.x) * 0.25f;
  float my_ = (v0.y + v1.y + v2.y + v3.y) * 0.25f;
  float mz_ = (v0.z + v1.z + v2.z + v3.z) * 0.25f;
  float mw_ = (v0.w + v1.w + v2.w + v3.w) * 0.25f;

  // logits = <v_k, pose0>
  float l0 = v0.x * mx_ + v0.y * my_ + v0.z * mz_ + v0.w * mw_;
  float l1 = v1.x * mx_ + v1.y * my_ + v1.z * mz_ + v1.w * mw_;
  float l2 = v2.x * mx_ + v2.y * my_ + v2.z * mz_ + v2.w * mw_;
  float l3 = v3.x * mx_ + v3.y * my_ + v3.z * mz_ + v3.w * mw_;

  // softmax over kk
  float lmax = fmaxf(fmaxf(l0, l1), fmaxf(l2, l3));
  float e0 = expf(l0 - lmax);
  float e1 = expf(l1 - lmax);
  float e2 = expf(l2 - lmax);
  float e3 = expf(l3 - lmax);
  float inv = 1.0f / (e0 + e1 + e2 + e3);
  float r0 = e0 * inv, r1 = e1 * inv, r2 = e2 * inv, r3 = e3 * inv;

  float4 o;
  o.x = r0 * v0.x + r1 * v1.x + r2 * v2.x + r3 * v3.x;
  o.y = r0 * v0.y + r1 * v1.y + r2 * v2.y + r3 * v3.y;
  o.z = r0 * v0.z + r1 * v1.z + r2 * v2.z + r3 * v3.z;
  o.w = r0 * v0.w + r1 * v1.w + r2 * v2.w + r3 * v3.w;

  out[idx] = o;
}

extern "C" void kernel_launch(void* const* d_in, const int* in_sizes, int n_in,
                              void* d_out, int out_size, void* d_ws, size_t ws_size,
                              hipStream_t stream) {
  const float4* x = (const float4*)d_in[0];
  float4* out = (float4*)d_out;
  const long total = (long)Bn * OH * OW * G;  // 2,097,152 threads
  const int block = 256;
  const int grid = (int)((total + block - 1) / block);  // 8192
  routing_pool_kernel<<<grid, block, 0, stream>>>(x, out);
}

// Round 6
// 193.112 us; speedup vs baseline: 1.0065x; 1.0065x over previous
//
#include <hip/hip_runtime.h>

// RoutingPooling: x [B=32, H=64, W=64, C=256] fp32 -> out [32, 32, 32, 256] fp32
// KERNEL=STRIDE=2 (non-overlapping), ATOMS=4, g=64 groups, NUM_ROUTING=2.
// Closed form per (b,i,j,group):
//   pose0 = mean(v0..v3); l_k = <v_k,pose0>; r = softmax(l); out = sum r_k v_k
//
// Traffic floor: 128 MB read (each element once) + 32 MB write = 160 MB -> ~25 us @6.3TB/s.
// R2 evidence: kernel absent from top-5 (all ~79us fill dispatches) => kernel < 78 us;
// timed dur_us=194 includes ~118us harness poison+restore. This round: 2 output
// positions per thread (8 outstanding 16B loads, 2x MLP) + nontemporal stores
// (via clang native vector type -- HIP float4 class is rejected by the builtin).

constexpr int Bn = 32, Hn = 64, Wn = 64;
constexpr int OH = 32, OW = 32, G = 64;  // G = C/ATOMS

typedef float nf4 __attribute__((ext_vector_type(4)));  // native vector for builtins

__device__ __forceinline__ float4 route4(const float4 v0, const float4 v1,
                                         const float4 v2, const float4 v3) {
  // pose0 = mean of the 4 votes
  float mx_ = (v0.x + v1.x + v2.x + v3.x) * 0.25f;
  float my_ = (v0.y + v1.y + v2.y + v3.y) * 0.25f;
  float mz_ = (v0.z + v1.z + v2.z + v3.z) * 0.25f;
  float mw_ = (v0.w + v1.w + v2.w + v3.w) * 0.25f;
  // logits = <v_k, pose0>
  float l0 = v0.x * mx_ + v0.y * my_ + v0.z * mz_ + v0.w * mw_;
  float l1 = v1.x * mx_ + v1.y * my_ + v1.z * mz_ + v1.w * mw_;
  float l2 = v2.x * mx_ + v2.y * my_ + v2.z * mz_ + v2.w * mw_;
  float l3 = v3.x * mx_ + v3.y * my_ + v3.z * mz_ + v3.w * mw_;
  // softmax over the 4 patch cells
  float lmax = fmaxf(fmaxf(l0, l1), fmaxf(l2, l3));
  float e0 = expf(l0 - lmax);
  float e1 = expf(l1 - lmax);
  float e2 = expf(l2 - lmax);
  float e3 = expf(l3 - lmax);
  float inv = 1.0f / (e0 + e1 + e2 + e3);
  float r0 = e0 * inv, r1 = e1 * inv, r2 = e2 * inv, r3 = e3 * inv;
  float4 o;
  o.x = r0 * v0.x + r1 * v1.x + r2 * v2.x + r3 * v3.x;
  o.y = r0 * v0.y + r1 * v1.y + r2 * v2.y + r3 * v3.y;
  o.z = r0 * v0.z + r1 * v1.z + r2 * v2.z + r3 * v3.z;
  o.w = r0 * v0.w + r1 * v1.w + r2 * v2.w + r3 * v3.w;
  return o;
}

__device__ __forceinline__ void nt_store(float4* p, const float4 v) {
  nf4 nv = {v.x, v.y, v.z, v.w};
  __builtin_nontemporal_store(nv, (nf4*)p);
}

__global__ __launch_bounds__(256) void routing_pool_kernel(
    const float4* __restrict__ x, float4* __restrict__ out) {
  // idx over (b, i, jh, gc), gc fastest (64 = one wave => coalesced float4).
  // Each thread handles output columns j0 = 2*jh and j0+1.
  int idx = blockIdx.x * 256 + threadIdx.x;
  int gc = idx & 63;
  int t = idx >> 6;
  int jh = t & 15; t >>= 4;
  int i  = t & 31; t >>= 5;
  int b  = t;
  int j0 = jh * 2;

  // x as float4: 64 per (b,h,w) position; row stride Wn*64 float4s
  const long rs = (long)Wn * 64;
  long base = (((long)b * Hn + 2 * i) * Wn + 2 * j0) * 64 + gc;

  // Issue all 8 independent loads up front (MLP).
  float4 a0 = x[base];
  float4 a1 = x[base + 64];
  float4 a2 = x[base + rs];
  float4 a3 = x[base + rs + 64];
  float4 b0 = x[base + 128];
  float4 b1 = x[base + 192];
  float4 b2 = x[base + rs + 128];
  float4 b3 = x[base + rs + 192];

  float4 oA = route4(a0, a1, a2, a3);
  float4 oB = route4(b0, b1, b2, b3);

  long oidx = (((long)b * OH + i) * OW + j0) * 64 + gc;
  nt_store(&out[oidx], oA);
  nt_store(&out[oidx + 64], oB);
}

extern "C" void kernel_launch(void* const* d_in, const int* in_sizes, int n_in,
                              void* d_out, int out_size, void* d_ws, size_t ws_size,
                              hipStream_t stream) {
  const float4* x = (const float4*)d_in[0];
  float4* out = (float4*)d_out;
  const long total = (long)Bn * OH * (OW / 2) * G;  // 1,048,576 threads
  const int block = 256;
  const int grid = (int)((total + block - 1) / block);  // 4096
  routing_pool_kernel<<<grid, block, 0, stream>>>(x, out);
}